// Round 10
// baseline (251.275 us; speedup 1.0000x reference)
//
#include <hip/hip_runtime.h>
#include <hip/hip_fp16.h>
#include <math.h>

#define N_DRUG 20000
#define N_PROT 30000
#define NN (N_DRUG + N_PROT)
#define F_DRUG 128
#define F_PROT 256
#define H 64
#define NE 1600000
#define NL 200000

#define NB_PROJD ((N_DRUG + 127) / 128)          // 157 (128 rows/block)
#define NB_PROJP ((N_PROT + 127) / 128)          // 235
#define NB_CONV  ((NN + 255) / 256)              // 196 (256 rows/block)
#define NB_ROW4  ((NN + 3) / 4)                  // 12500 (4 rows/block, warp per row)
#define NBK1 256                                  // partition chunks
#define CH   ((NE + NBK1 - 1) / NBK1)            // 6250 edges/chunk
#define NB_BKT ((NN + 255) / 256)                // 196 buckets

typedef _Float16 h8 __attribute__((ext_vector_type(8)));
typedef _Float16 h4 __attribute__((ext_vector_type(4)));
typedef float f32x4 __attribute__((ext_vector_type(4)));

#define MFMA16(a, b, c) __builtin_amdgcn_mfma_f32_16x16x32_f16((a), (b), (c), 0, 0, 0)

// ---------------- weight prep: transpose + fp16 ([c][k] layout) ----------------
__global__ __launch_bounds__(256) void k_wprep(
    const float* __restrict__ Wd, const float* __restrict__ Wp,
    const float* __restrict__ cw,
    _Float16* __restrict__ wdt, _Float16* __restrict__ wpt,
    _Float16* __restrict__ cwt) {
    int i = blockIdx.x * 256 + threadIdx.x;
    if (i < 64 * F_DRUG) {
        int c = i / F_DRUG, k = i % F_DRUG;
        wdt[i] = (_Float16)Wd[k * H + c];
    }
    if (i < 64 * F_PROT) {
        int c = i / F_PROT, k = i % F_PROT;
        wpt[i] = (_Float16)Wp[k * H + c];
    }
    if (i < 3 * 64 * 64) {
        int l = i >> 12, r = i & 4095;
        int c = r >> 6, k = r & 63;
        cwt[i] = (_Float16)cw[(l << 12) + k * H + c];
    }
}

// ---------------- zero-LDS MFMA projection -> split lo/hi fp16 x ----------------
template <int F>
__device__ __forceinline__ void proj_direct(
    const float* __restrict__ X, const _Float16* __restrict__ Wt,
    const float* __restrict__ bias,
    _Float16* __restrict__ xlo, _Float16* __restrict__ xhi,
    int rows, int row_off, int bid) {
    int l = threadIdx.x & 63, wvi = threadIdx.x >> 6;
    int lr = l & 15, lq = l >> 4;
    int r0 = bid * 128 + wvi * 32;
    f32x4 acc[2][4];
    #pragma unroll
    for (int rt = 0; rt < 2; ++rt)
        #pragma unroll
        for (int n = 0; n < 4; ++n) acc[rt][n] = (f32x4){0.f, 0.f, 0.f, 0.f};

    for (int k0 = 0; k0 < F; k0 += 64) {
        h8 af[4][2];
        #pragma unroll
        for (int n = 0; n < 4; ++n)
            #pragma unroll
            for (int kk = 0; kk < 2; ++kk)
                af[n][kk] = *(const h8*)&Wt[(size_t)(n * 16 + lr) * F + k0 + kk * 32 + lq * 8];
        #pragma unroll
        for (int rt = 0; rt < 2; ++rt) {
            int r = r0 + rt * 16 + lr;
            int rc = (r < rows) ? r : (rows - 1);
            h8 bf[2];
            #pragma unroll
            for (int kk = 0; kk < 2; ++kk) {
                const float* xp = X + (size_t)rc * F + k0 + kk * 32 + lq * 8;
                float4 a = *(const float4*)xp;
                float4 b = *(const float4*)(xp + 4);
                h8 t;
                t[0] = (_Float16)a.x; t[1] = (_Float16)a.y;
                t[2] = (_Float16)a.z; t[3] = (_Float16)a.w;
                t[4] = (_Float16)b.x; t[5] = (_Float16)b.y;
                t[6] = (_Float16)b.z; t[7] = (_Float16)b.w;
                bf[kk] = t;
            }
            #pragma unroll
            for (int n = 0; n < 4; ++n) {
                acc[rt][n] = MFMA16(af[n][0], bf[0], acc[rt][n]);
                acc[rt][n] = MFMA16(af[n][1], bf[1], acc[rt][n]);
            }
        }
    }
    #pragma unroll
    for (int rt = 0; rt < 2; ++rt) {
        int r = r0 + rt * 16 + lr;
        if (r < rows) {
            #pragma unroll
            for (int n = 0; n < 4; ++n) {
                int c = n * 16 + lq * 4;
                float4 bv = *(const float4*)&bias[c];
                h4 hv;
                hv[0] = (_Float16)fmaxf(acc[rt][n][0] + bv.x, 0.f);
                hv[1] = (_Float16)fmaxf(acc[rt][n][1] + bv.y, 0.f);
                hv[2] = (_Float16)fmaxf(acc[rt][n][2] + bv.z, 0.f);
                hv[3] = (_Float16)fmaxf(acc[rt][n][3] + bv.w, 0.f);
                _Float16* dst = (n < 2)
                    ? (xlo + (size_t)(row_off + r) * 32 + c)
                    : (xhi + (size_t)(row_off + r) * 32 + (c - 32));
                *(h4*)dst = hv;
            }
        }
    }
}

// ---------------- zero-LDS MFMA conv: split lo/hi in, split lo/hi out ----------------
__device__ __forceinline__ void conv_direct(
    const _Float16* __restrict__ xlo, const _Float16* __restrict__ xhi,
    const _Float16* __restrict__ Wt,
    _Float16* __restrict__ olo, _Float16* __restrict__ ohi, int bid) {
    int l = threadIdx.x & 63, wvi = threadIdx.x >> 6;
    int lr = l & 15, lq = l >> 4;
    h8 af[4][2];
    #pragma unroll
    for (int n = 0; n < 4; ++n)
        #pragma unroll
        for (int kk = 0; kk < 2; ++kk)
            af[n][kk] = *(const h8*)&Wt[(size_t)(n * 16 + lr) * 64 + kk * 32 + lq * 8];
    int r0 = bid * 256 + wvi * 64;
    #pragma unroll
    for (int rt = 0; rt < 4; ++rt) {
        int r = r0 + rt * 16 + lr;
        int rc = (r < NN) ? r : (NN - 1);
        h8 bf0 = *(const h8*)&xlo[(size_t)rc * 32 + lq * 8];   // k = 0..31
        h8 bf1 = *(const h8*)&xhi[(size_t)rc * 32 + lq * 8];   // k = 32..63
        f32x4 a[4];
        #pragma unroll
        for (int n = 0; n < 4; ++n) {
            a[n] = (f32x4){0.f, 0.f, 0.f, 0.f};
            a[n] = MFMA16(af[n][0], bf0, a[n]);
            a[n] = MFMA16(af[n][1], bf1, a[n]);
        }
        if (r < NN) {
            #pragma unroll
            for (int n = 0; n < 4; ++n) {
                int c = n * 16 + lq * 4;
                h4 hv;
                hv[0] = (_Float16)a[n][0]; hv[1] = (_Float16)a[n][1];
                hv[2] = (_Float16)a[n][2]; hv[3] = (_Float16)a[n][3];
                _Float16* dst = (n < 2)
                    ? (olo + (size_t)r * 32 + c)
                    : (ohi + (size_t)r * 32 + (c - 32));
                *(h4*)dst = hv;
            }
        }
    }
}

// ---------------- fused front: proj_drug || proj_prot || coarse bucket hist ----------------
__global__ __launch_bounds__(256) void k_front(
    const float* __restrict__ xd, const _Float16* __restrict__ wdt, const float* __restrict__ bd,
    const float* __restrict__ xp, const _Float16* __restrict__ wpt, const float* __restrict__ bp,
    const int* __restrict__ ei, unsigned* __restrict__ bhist,
    _Float16* __restrict__ xlo, _Float16* __restrict__ xhi) {
    __shared__ unsigned lh[256];
    int bid = blockIdx.x;
    if (bid < NB_PROJD) {
        proj_direct<F_DRUG>(xd, wdt, bd, xlo, xhi, N_DRUG, 0, bid);
    } else if (bid < NB_PROJD + NB_PROJP) {
        proj_direct<F_PROT>(xp, wpt, bp, xlo, xhi, N_PROT, N_DRUG, bid - NB_PROJD);
    } else {
        int blk = bid - NB_PROJD - NB_PROJP;
        int t = threadIdx.x;
        lh[t] = 0;
        __syncthreads();
        int eb = blk * CH, ee = min(NE, eb + CH);
        for (int e = eb + t; e < ee; e += 256)
            atomicAdd(&lh[((unsigned)ei[NE + e]) >> 8], 1u);
        __syncthreads();
        bhist[(size_t)t * NBK1 + blk] = lh[t];
    }
}

// ---------------- scan step A: per-bucket row sums ----------------
__global__ __launch_bounds__(256) void kA(const unsigned* __restrict__ bhist,
                                          unsigned* __restrict__ rsum) {
    __shared__ unsigned s[256];
    int j = blockIdx.x, t = threadIdx.x;
    s[t] = bhist[(size_t)j * NBK1 + t];
    __syncthreads();
    for (int off = 128; off; off >>= 1) {
        if (t < off) s[t] += s[t + off];
        __syncthreads();
    }
    if (t == 0) rsum[j] = s[0];
}

// ---------------- scan step B: exclusive scan of bucket totals ----------------
__global__ __launch_bounds__(256) void kB(const unsigned* __restrict__ rsum,
                                          unsigned* __restrict__ rbase) {
    __shared__ unsigned s[256];
    int t = threadIdx.x;
    unsigned c = rsum[t];
    s[t] = c;
    __syncthreads();
    for (int off = 1; off < 256; off <<= 1) {
        unsigned v = s[t]; unsigned u = (t >= off) ? s[t - off] : 0;
        __syncthreads(); s[t] = v + u; __syncthreads();
    }
    rbase[t] = s[t] - c;
    if (t == 255) rbase[256] = s[255];
}

// ---------------- scan step C: per-bucket row exclusive scan + offset ----------------
__global__ __launch_bounds__(256) void kC(unsigned* __restrict__ bhist,
                                          const unsigned* __restrict__ rbase) {
    __shared__ unsigned s[256];
    int j = blockIdx.x, t = threadIdx.x;
    unsigned c = bhist[(size_t)j * NBK1 + t];
    s[t] = c;
    __syncthreads();
    for (int off = 1; off < 256; off <<= 1) {
        unsigned v = s[t]; unsigned u = (t >= off) ? s[t - off] : 0;
        __syncthreads(); s[t] = v + u; __syncthreads();
    }
    bhist[(size_t)j * NBK1 + t] = rbase[j] + s[t] - c;
}

// ---------------- bucket partition-scatter, XCD-contiguous chunk remap ----------------
__global__ __launch_bounds__(256) void k_part(
    const int* __restrict__ ei, const unsigned* __restrict__ base,
    unsigned* __restrict__ tmp) {
    __shared__ unsigned lcur[256];
    int bid = blockIdx.x;
    int c = ((bid & 7) << 5) | (bid >> 3);   // XCD-contiguous chunk id
    int t = threadIdx.x;
    lcur[t] = base[(size_t)t * NBK1 + c];
    __syncthreads();
    int eb = c * CH, ee = min(NE, eb + CH);
    for (int e = eb + t; e < ee; e += 256) {
        unsigned s = (unsigned)ei[e];
        unsigned d = (unsigned)ei[NE + e];
        unsigned pos = atomicAdd(&lcur[d >> 8], 1u);
        tmp[pos] = ((d & 255u) << 16) | s;
    }
}

// ---------------- fused: per-bucket CSR finalize || conv layer 0 ----------------
__global__ __launch_bounds__(256) void k_csrconv(
    const unsigned* __restrict__ tmp, const unsigned* __restrict__ rbase,
    int* __restrict__ rp, float* __restrict__ dis, unsigned short* __restrict__ csr,
    const _Float16* __restrict__ xlo, const _Float16* __restrict__ xhi,
    const _Float16* __restrict__ cwt,
    _Float16* __restrict__ olo, _Float16* __restrict__ ohi) {
    __shared__ unsigned lbin[256], lofs[256], lcur[256];
    int bid = blockIdx.x;
    if (bid >= NB_BKT) {
        conv_direct(xlo, xhi, cwt, olo, ohi, bid - NB_BKT);
        return;
    }
    int b = bid, t = threadIdx.x;
    unsigned nb0 = rbase[b], nb1 = rbase[b + 1];
    lbin[t] = 0;
    __syncthreads();
    for (unsigned i = nb0 + t; i < nb1; i += 256)
        atomicAdd(&lbin[tmp[i] >> 16], 1u);
    __syncthreads();
    unsigned c = lbin[t];
    lofs[t] = c;
    __syncthreads();
    for (int off = 1; off < 256; off <<= 1) {
        unsigned v = lofs[t]; unsigned u = (t >= off) ? lofs[t - off] : 0;
        __syncthreads(); lofs[t] = v + u; __syncthreads();
    }
    unsigned r = nb0 + lofs[t] - c;
    int node = b * 256 + t;
    if (node < NN) {
        rp[node] = (int)r;
        dis[node] = rsqrtf((float)c + 1.0f);
    }
    lcur[t] = r;
    __syncthreads();
    for (unsigned i = nb0 + t; i < nb1; i += 256) {
        unsigned rec = tmp[i];
        unsigned pos = atomicAdd(&lcur[rec >> 16], 1u);
        csr[pos] = (unsigned short)(rec & 0xffffu);
    }
    if (b == 0 && t == 0) rp[NN] = NE;
}

// ---------------- standalone conv (layers 1,2) ----------------
__global__ __launch_bounds__(256) void k_conv(
    const _Float16* __restrict__ xlo, const _Float16* __restrict__ xhi,
    const _Float16* __restrict__ Wt,
    _Float16* __restrict__ olo, _Float16* __restrict__ ohi) {
    conv_direct(xlo, xhi, Wt, olo, ohi, blockIdx.x);
}

// ---------------- SpMM half-row pass: 32-feature slice (3.2 MB table, L2-resident) ----------------
// lane: q = lane>>3 (8 edge slots), g = lane&7 (features 4g..4g+3 of the slice).
// FIRST: also builds pack[] = src | f16(dis_s*dis_d)<<16.
template <bool FIRST, bool LAST>
__global__ __launch_bounds__(256) void k_spmm2(
    const int* __restrict__ rp, const unsigned short* __restrict__ csr,
    unsigned* __restrict__ pack, const float* __restrict__ dis,
    const _Float16* __restrict__ xws /* [NN][32] slice */,
    const float* __restrict__ bias32, _Float16* __restrict__ xouts /* [NN][32] */,
    const float* __restrict__ lw32, float* __restrict__ ypart) {
    int lane = threadIdx.x & 63;
    int d = blockIdx.x * 4 + (threadIdx.x >> 6);
    if (d >= NN) return;
    int q = lane >> 3, g = lane & 7;
    int beg = rp[d], end = rp[d + 1];
    float dd = dis[d];
    float ax = 0.f, ay = 0.f, az = 0.f, aw = 0.f;

    int n = end - beg; if (n > 64) n = 64;
    unsigned rv = 0;
    if (lane < n) {
        if (FIRST) {
            int s = csr[beg + lane];
            float w0 = dis[s] * dd;
            rv = (unsigned)s | ((unsigned)__half_as_ushort(__float2half(w0)) << 16);
            pack[beg + lane] = rv;
        } else rv = __builtin_nontemporal_load(&pack[beg + lane]);
    }
    for (int b0 = beg; b0 < end; ) {
        int nb = b0 + 64;
        int n2 = end - nb; if (n2 > 64) n2 = 64;
        unsigned rv2 = 0;
        if (n2 > 0 && lane < n2) {
            if (FIRST) {
                int s = csr[nb + lane];
                float w0 = dis[s] * dd;
                rv2 = (unsigned)s | ((unsigned)__half_as_ushort(__float2half(w0)) << 16);
                pack[nb + lane] = rv2;
            } else rv2 = __builtin_nontemporal_load(&pack[nb + lane]);
        }
        int nsteps = (n + 7) >> 3;
        for (int j0 = 0; j0 < nsteps; j0 += 4) {
            int m = nsteps - j0; if (m > 4) m = 4;
            h4 xv[4]; float wv[4];
            #pragma unroll
            for (int k = 0; k < 4; ++k) {
                if (k < m) {
                    unsigned r = __shfl(rv, (j0 + k) * 8 + q);   // r==0 masks idx>=n
                    wv[k] = __half2float(__ushort_as_half((unsigned short)(r >> 16)));
                    xv[k] = *(const h4*)&xws[((r & 0xffffu) << 5) + (g << 2)];
                }
            }
            #pragma unroll
            for (int k = 0; k < 4; ++k) {
                if (k < m) {
                    ax += wv[k] * (float)xv[k][0];
                    ay += wv[k] * (float)xv[k][1];
                    az += wv[k] * (float)xv[k][2];
                    aw += wv[k] * (float)xv[k][3];
                }
            }
        }
        b0 = nb; n = n2; rv = rv2;
    }
    // reduce across the 8 q-groups
    #pragma unroll
    for (int off = 8; off < 64; off <<= 1) {
        ax += __shfl_xor(ax, off); ay += __shfl_xor(ay, off);
        az += __shfl_xor(az, off); aw += __shfl_xor(aw, off);
    }

    // epilogue: self term + bias + relu (edge weights pre-multiplied)
    float sn = dd * dd;
    h4 xs = *(const h4*)&xws[((unsigned)d << 5) + (g << 2)];
    float4 bv = *(const float4*)&bias32[g << 2];
    float vx = fmaxf(ax + sn * (float)xs[0] + bv.x, 0.f);
    float vy = fmaxf(ay + sn * (float)xs[1] + bv.y, 0.f);
    float vz = fmaxf(az + sn * (float)xs[2] + bv.z, 0.f);
    float vw = fmaxf(aw + sn * (float)xs[3] + bv.w, 0.f);
    if (LAST) {
        float4 lv = *(const float4*)&lw32[g << 2];
        float t = vx * lv.x + vy * lv.y + vz * lv.z + vw * lv.w;
        t += __shfl_xor(t, 1); t += __shfl_xor(t, 2); t += __shfl_xor(t, 4);
        if (lane == 0) ypart[d] = t;
    } else if (q == 0) {
        h4 hv;
        hv[0] = (_Float16)vx; hv[1] = (_Float16)vy;
        hv[2] = (_Float16)vz; hv[3] = (_Float16)vw;
        *(h4*)(xouts + ((size_t)d << 5) + (g << 2)) = hv;
    }
}

// ---------------- edge scoring: sigmoid((ylo+yhi+lb)[s] * (ylo+yhi+lb)[t]) ----------------
__global__ void k_out(const float* __restrict__ ylo, const float* __restrict__ yhi,
                      const float* __restrict__ lb,
                      const int* __restrict__ ls, const int* __restrict__ ld,
                      float* __restrict__ out) {
    int e = blockIdx.x * blockDim.x + threadIdx.x;
    if (e < NL) {
        float b = lb[0];
        int s = ls[e], t = ld[e];
        float sd = ylo[s] + yhi[s] + b;
        float sp = ylo[t] + yhi[t] + b;
        float z = sd * sp;
        out[e] = 1.f / (1.f + __expf(-z));
    }
}

static inline size_t up256(size_t x) { return (x + 255) & ~(size_t)255; }

extern "C" void kernel_launch(void* const* d_in, const int* in_sizes, int n_in,
                              void* d_out, int out_size, void* d_ws, size_t ws_size,
                              hipStream_t stream) {
    const float* x_drug = (const float*)d_in[0];
    const float* x_prot = (const float*)d_in[1];
    const float* W_drug = (const float*)d_in[2];
    const float* b_drug = (const float*)d_in[3];
    const float* W_prot = (const float*)d_in[4];
    const float* b_prot = (const float*)d_in[5];
    const float* conv_W = (const float*)d_in[6];
    const float* conv_b = (const float*)d_in[7];
    const float* lin_W  = (const float*)d_in[8];
    const float* lin_b  = (const float*)d_in[9];
    const int*   ei     = (const int*)d_in[10];
    const int*   lsrc   = (const int*)d_in[11];
    const int*   ldst   = (const int*)d_in[12];
    float* out = (float*)d_out;

    char* w = (char*)d_ws;
    size_t off = 0;
    unsigned* bhist = (unsigned*)(w + off); off = up256(off + (size_t)256 * NBK1 * 4);
    unsigned* rsum  = (unsigned*)(w + off); off = up256(off + 256 * 4);
    unsigned* rbase = (unsigned*)(w + off); off = up256(off + 257 * 4);
    unsigned* tmp   = (unsigned*)(w + off); off = up256(off + (size_t)NE * 4);
    unsigned short* csr = (unsigned short*)(w + off); off = up256(off + (size_t)NE * 2);
    unsigned* pack  = (unsigned*)(w + off); off = up256(off + (size_t)NE * 4);
    int*    rp   = (int*)(w + off);    off = up256(off + (size_t)(NN + 1) * 4);
    float*  dis  = (float*)(w + off);  off = up256(off + (size_t)NN * 4);
    _Float16* xblo = (_Float16*)(w + off); off = up256(off + (size_t)NN * 32 * 2);
    _Float16* xbhi = (_Float16*)(w + off); off = up256(off + (size_t)NN * 32 * 2);
    _Float16* xwlo = (_Float16*)(w + off); off = up256(off + (size_t)NN * 32 * 2);
    _Float16* xwhi = (_Float16*)(w + off); off = up256(off + (size_t)NN * 32 * 2);
    float*  ylo  = (float*)(w + off);  off = up256(off + (size_t)NN * 4);
    float*  yhi  = (float*)(w + off);  off = up256(off + (size_t)NN * 4);
    _Float16* wdt = (_Float16*)(w + off); off = up256(off + (size_t)64 * F_DRUG * 2);
    _Float16* wpt = (_Float16*)(w + off); off = up256(off + (size_t)64 * F_PROT * 2);
    _Float16* cwt = (_Float16*)(w + off); off = up256(off + (size_t)3 * 64 * 64 * 2);

    k_wprep<<<64, 256, 0, stream>>>(W_drug, W_prot, conv_W, wdt, wpt, cwt);

    // proj_drug || proj_prot || coarse hist
    k_front<<<NB_PROJD + NB_PROJP + NBK1, 256, 0, stream>>>(
        x_drug, wdt, b_drug, x_prot, wpt, b_prot, ei, bhist, xblo, xbhi);

    kA<<<256, 256, 0, stream>>>(bhist, rsum);
    kB<<<1, 256, 0, stream>>>(rsum, rbase);
    kC<<<256, 256, 0, stream>>>(bhist, rbase);

    // bucket partition-scatter (XCD-contiguous chunks)
    k_part<<<NBK1, 256, 0, stream>>>(ei, bhist, tmp);

    // per-bucket CSR finalize || conv layer 0
    k_csrconv<<<NB_BKT + NB_CONV, 256, 0, stream>>>(
        tmp, rbase, rp, dis, csr, xblo, xbhi, cwt, xwlo, xwhi);

    // layer 0 (lo builds pack)
    k_spmm2<true, false><<<NB_ROW4, 256, 0, stream>>>(
        rp, csr, pack, dis, xwlo, conv_b, xblo, nullptr, nullptr);
    k_spmm2<false, false><<<NB_ROW4, 256, 0, stream>>>(
        rp, csr, pack, dis, xwhi, conv_b + 32, xbhi, nullptr, nullptr);
    // layer 1
    k_conv<<<NB_CONV, 256, 0, stream>>>(xblo, xbhi, cwt + 4096, xwlo, xwhi);
    k_spmm2<false, false><<<NB_ROW4, 256, 0, stream>>>(
        rp, csr, pack, dis, xwlo, conv_b + 64, xblo, nullptr, nullptr);
    k_spmm2<false, false><<<NB_ROW4, 256, 0, stream>>>(
        rp, csr, pack, dis, xwhi, conv_b + 96, xbhi, nullptr, nullptr);
    // layer 2 (fused partial-y epilogues)
    k_conv<<<NB_CONV, 256, 0, stream>>>(xblo, xbhi, cwt + 8192, xwlo, xwhi);
    k_spmm2<false, true><<<NB_ROW4, 256, 0, stream>>>(
        rp, csr, pack, dis, xwlo, conv_b + 128, nullptr, lin_W, ylo);
    k_spmm2<false, true><<<NB_ROW4, 256, 0, stream>>>(
        rp, csr, pack, dis, xwhi, conv_b + 160, nullptr, lin_W + 32, yhi);

    k_out<<<(NL + 255) / 256, 256, 0, stream>>>(ylo, yhi, lin_b, lsrc, ldst, out);
}